// Round 24
// baseline (41.616 us; speedup 1.0000x reference)
//
#include <hip/hip_runtime.h>
#include <math.h>

#define BB 4
#define CC 64
#define NN 4096
#define IND 8
#define HF 32
#define QBLK 64
#define THREADS 512
#define WAVES 8
#define MBLK 32
#define MCHUNK (NN/WAVES)    // 512 m's per wave
#define NBLK (MCHUNK/MBLK)   // 16 blocks
#define PREP 3               // R24 instrument: prologue reps (idempotent)
#define EREP 3               // R24 instrument: post-loop reps (idempotent via sred)

typedef __attribute__((ext_vector_type(8))) short bf16x8;
typedef __attribute__((ext_vector_type(4))) float f32x4;

static __device__ __forceinline__ unsigned short f2bf(float x) {
    unsigned int u = __float_as_uint(x);
    u = (u + 0x7FFFu + ((u >> 16) & 1u)) >> 16;   // RNE
    return (unsigned short)u;
}
static __device__ __forceinline__ float bf2f(unsigned short h) {
    return __uint_as_float(((unsigned int)h) << 16);
}
// native __bf16 casts -> v_cvt_pk_bf16_f32 path (R17, kept)
static __device__ __forceinline__ unsigned int pk2(float lo, float hi) {
    __bf16 l = (__bf16)lo, h = (__bf16)hi;
    unsigned short ul = __builtin_bit_cast(unsigned short, l);
    unsigned short uh = __builtin_bit_cast(unsigned short, h);
    return (unsigned int)ul | ((unsigned int)uh << 16);
}
static __device__ __forceinline__ float ex2(float x) {
    return __builtin_amdgcn_exp2f(x);   // v_exp_f32 (2^x)
}

// m -> k-slot coding shared by P (in-register) and V (blocked layout):
// k(m5) = (m5&3) | ((m5>>4)&1)<<2 | ((m5>>2)&3)<<3   (bijective on 0..31)
// V layout: vblk[b][mb][hg][c15][ks] u16 (2 KB per mb) -> contiguous wave-load.
//
// R24 NOTE: MEASUREMENT ROUND. R20 data implies attn's prologue+post-loop
// ~16-19 us >> loop 11.5 us (cross-binary, codegen-confounded). This round
// reps prologue (PREP=3) and post-loop (EREP=3, reduce into separate sred
// so it's idempotent) with opaque-zero offsets: T24 - T22 = 2*(P+E).

// Kernel 1: 1x1-conv projections -> packed bf16 workspaces. (R22 form, frozen)
__global__ __launch_bounds__(128) void proj_kernel(
    const float* __restrict__ xsrc,
    const float* __restrict__ Wf, const float* __restrict__ bf,
    const float* __restrict__ Wg, const float* __restrict__ bg,
    const float* __restrict__ Wh, const float* __restrict__ bh,
    unsigned short* __restrict__ fpk,
    unsigned short* __restrict__ gpk,
    unsigned short* __restrict__ vblk)
{
    __shared__ float swT[CC][8];       // [c][o], 2 KB

    int tid = threadIdx.x;
    int bx  = blockIdx.x;
    int og  = bx >> 7;                 // 0..5 (block-uniform)
    int r   = bx & 127;
    int xcd = r & 7;
    int b   = xcd >> 1;
    int blk = ((xcd & 1) << 4) + (r >> 3);
    int n   = blk * 128 + tid;

    const float* W;
    const float* bias;
    if (og == 0)      { W = Wf; bias = bf; }
    else if (og == 1) { W = Wg; bias = bg; }
    else              { W = Wh + (og - 2) * 8 * CC; bias = bh + (og - 2) * 8; }

    // stage W -> LDS transposed (one-time)
    {
        float4 wv = *(const float4*)(W + tid * 4);   // coalesced
        int o = (tid * 4) >> 6;
        int c0 = (tid * 4) & 63;
        swT[c0 + 0][o] = wv.x;
        swT[c0 + 1][o] = wv.y;
        swT[c0 + 2][o] = wv.z;
        swT[c0 + 3][o] = wv.w;
    }

    // issue all 64 coalesced loads, then pin them live before any FMA
    float xv[CC];
    {
        const float* xp = xsrc + (size_t)b * CC * NN + n;
        #pragma unroll
        for (int c = 0; c < CC; c++) xv[c] = xp[(size_t)c * NN];
    }
    #pragma unroll
    for (int c = 0; c < CC; c++) asm volatile("" : "+v"(xv[c]));

    __syncthreads();

    float a[8];
    #pragma unroll
    for (int o = 0; o < 8; o++) a[o] = bias[o];
    #pragma unroll
    for (int c = 0; c < CC; c++) {
        float4 w0 = *(const float4*)&swT[c][0];   // ds_read_b128, broadcast
        float4 w1 = *(const float4*)&swT[c][4];
        float v = xv[c];
        a[0] += w0.x * v; a[1] += w0.y * v; a[2] += w0.z * v; a[3] += w0.w * v;
        a[4] += w1.x * v; a[5] += w1.y * v; a[6] += w1.z * v; a[7] += w1.w * v;
    }

    const float LOG2E = 1.4426950408889634f;
    size_t base = (size_t)b * NN + n;

    if (og == 0) {
        union { unsigned short s[16]; uint4 q[2]; } fo;
        #pragma unroll
        for (int o = 0; o < 8; o++) {
            unsigned short hi = f2bf(a[o]);
            unsigned short lo = f2bf(a[o] - bf2f(hi));
            fo.s[o] = hi; fo.s[8 + o] = lo;
        }
        uint4* fdst = (uint4*)(fpk + base * 16);
        fdst[0] = fo.q[0]; fdst[1] = fo.q[1];
    } else if (og == 1) {
        union { unsigned short s[32]; uint4 q[4]; } go;
        #pragma unroll
        for (int o = 0; o < 8; o++) {
            float gsc = a[o] * LOG2E;              // exp -> exp2 fold
            unsigned short hi = f2bf(gsc);
            unsigned short lo = f2bf(gsc - bf2f(hi));
            go.s[o] = hi; go.s[8 + o] = hi; go.s[16 + o] = lo; go.s[24 + o] = lo;
        }
        uint4* gdst = (uint4*)(gpk + base * 32);
        #pragma unroll
        for (int k = 0; k < 4; k++) gdst[k] = go.q[k];
    } else {
        int m5 = n & 31;
        int code = (m5 & 3) | (((m5 >> 4) & 1) << 2) | (((m5 >> 2) & 3) << 3);
        int mb = (n >> 5);                          // m-block within batch
        int h0 = (og - 2) * 8;
        int hg = h0 >> 4;                           // block-uniform
        unsigned short* vp = vblk + (size_t)b * (NN/32) * 1024
                           + (size_t)mb * 1024 + hg * 512 + code;
        #pragma unroll
        for (int o = 0; o < 8; o++)
            vp[((h0 + o) & 15) * 32] = f2bf(a[o]);
    }
}

// Kernel 2: register-only MFMA flash attention + fused Wv/gamma/residual.
// R22 loop (2-stage A/B pipeline); prologue and post-loop instrumented x3.
__global__ __launch_bounds__(THREADS, 2) void attn_kernel(
    const unsigned short* __restrict__ fpk,
    const unsigned short* __restrict__ gpk,
    const unsigned short* __restrict__ vblk,
    const float* __restrict__ Wv, const float* __restrict__ bv,
    const float* __restrict__ gamma,
    const float* __restrict__ x, float* __restrict__ out)
{
    __shared__ float sl[WAVES][QBLK][HF + 1];   // 67.6 KB
    __shared__ float sred[QBLK][HF + 1];        // +8.5 KB (idempotent reduce dst)

    int tid  = threadIdx.x;
    int wave = tid >> 6;
    int lane = tid & 63;
    int c15  = lane & 15;
    int g4   = lane >> 4;

    // bijective XCD swizzle: 256 blocks = 8 XCD x 32 contiguous logical ids
    int l  = (blockIdx.x & 7) * 32 + (blockIdx.x >> 3);
    int b  = l >> 6;                  // 64 q-tiles per batch
    int n0 = (l & 63) * QBLK;

    f32x4 zero4 = {0.f, 0.f, 0.f, 0.f};
    bf16x8 bq[4];
    f32x4 acc[4][2];
    f32x4 accL[4];

    // ---- prologue, repped x3 (idempotent; opaque zoff defeats CSE) ----
    int zoff = 0;
    #pragma unroll 1
    for (int pr = 0; pr < PREP; pr++) {
        asm volatile("" : "+v"(zoff));   // opaque 0
        #pragma unroll
        for (int qg = 0; qg < 4; qg++)
            bq[qg] = *(const bf16x8*)(fpk
                      + ((size_t)(b * NN + n0 + qg*16 + c15)) * 16
                      + (g4 & 1) * 8 + zoff);
        #pragma unroll
        for (int qg = 0; qg < 4; qg++) {
            acc[qg][0] = zero4; acc[qg][1] = zero4; accL[qg] = zero4;
        }
    }

    const short one_bf = (short)0x3F80;   // 1.0 bf16
    const bf16x8 vones = {one_bf, one_bf, one_bf, one_bf,
                          one_bf, one_bf, one_bf, one_bf};

    // hoisted per-lane bases: per t just + t*1024 (u16) on each
    const unsigned short* gp = gpk  + (size_t)b * NN * 32
                             + ((size_t)(wave * MCHUNK + c15)) * 32 + g4*8;
    const unsigned short* vp = vblk + (size_t)b * (NN/32) * 1024
                             + (size_t)(wave * NBLK) * 1024 + c15*32 + g4*8;

#define PREFETCH(tt, ak, vb) do {                                   \
        const unsigned short* g_ = gp + (size_t)(tt) * 1024;        \
        const unsigned short* v_ = vp + (size_t)(tt) * 1024;        \
        ak[0] = *(const bf16x8*)(g_);                               \
        ak[1] = *(const bf16x8*)(g_ + 512);                         \
        vb[0] = *(const bf16x8*)(v_);                               \
        vb[1] = *(const bf16x8*)(v_ + 512);                         \
    } while (0)

#define COMPUTE(ak, vb) do {                                        \
        f32x4 sf[4][2];                                             \
        __builtin_amdgcn_s_setprio(1);                              \
        _Pragma("unroll")                                           \
        for (int mg = 0; mg < 2; mg++)                              \
            _Pragma("unroll")                                       \
            for (int qg = 0; qg < 4; qg++)                          \
                sf[qg][mg] = __builtin_amdgcn_mfma_f32_16x16x32_bf16( \
                    ak[mg], bq[qg], zero4, 0, 0, 0);                \
        __builtin_amdgcn_s_setprio(0);                              \
        bf16x8 pa[4];                                               \
        _Pragma("unroll")                                           \
        for (int qg = 0; qg < 4; qg++) {                            \
            float e00 = ex2(sf[qg][0][0]), e01 = ex2(sf[qg][0][1]); \
            float e02 = ex2(sf[qg][0][2]), e03 = ex2(sf[qg][0][3]); \
            float e10 = ex2(sf[qg][1][0]), e11 = ex2(sf[qg][1][1]); \
            float e12 = ex2(sf[qg][1][2]), e13 = ex2(sf[qg][1][3]); \
            union { unsigned int u[4]; bf16x8 v; } pp;              \
            pp.u[0] = pk2(e00, e01); pp.u[1] = pk2(e02, e03);       \
            pp.u[2] = pk2(e10, e11); pp.u[3] = pk2(e12, e13);       \
            pa[qg] = pp.v;                                          \
        }                                                           \
        __builtin_amdgcn_s_setprio(1);                              \
        _Pragma("unroll")                                           \
        for (int qg = 0; qg < 4; qg++) {                            \
            _Pragma("unroll")                                       \
            for (int hg = 0; hg < 2; hg++)                          \
                acc[qg][hg] = __builtin_amdgcn_mfma_f32_16x16x32_bf16( \
                    pa[qg], vb[hg], acc[qg][hg], 0, 0, 0);          \
            accL[qg] = __builtin_amdgcn_mfma_f32_16x16x32_bf16(     \
                    pa[qg], vones, accL[qg], 0, 0, 0);              \
        }                                                           \
        __builtin_amdgcn_s_setprio(0);                              \
    } while (0)

    bf16x8 akA[2], vbA[2], akB[2], vbB[2];
    PREFETCH(0, akA, vbA);

    #pragma unroll 2
    for (int tp = 0; tp < NBLK; tp += 2) {
        PREFETCH(tp + 1, akB, vbB);          // tp+1 <= 15: always valid
        COMPUTE(akA, vbA);                   // even t
        if (tp + 2 < NBLK) PREFETCH(tp + 2, akA, vbA);
        COMPUTE(akB, vbB);                   // odd t
    }
#undef PREFETCH
#undef COMPUTE

    // ---- post-loop (combine -> reduce -> projection), repped x3 ----
    int zoff2 = 0;
    #pragma unroll 1
    for (int er = 0; er < EREP; er++) {
        asm volatile("" : "+v"(zoff2));   // opaque 0

        // deterministic wave combine (idempotent: same values each rep)
        #pragma unroll
        for (int qg = 0; qg < 4; qg++)
            #pragma unroll
            for (int hg = 0; hg < 2; hg++)
                #pragma unroll
                for (int r = 0; r < 4; r++)
                    sl[wave][qg*16 + g4*4 + r][hg*16 + c15] = acc[qg][hg][r];
        if (c15 == 0) {
            #pragma unroll
            for (int qg = 0; qg < 4; qg++)
                #pragma unroll
                for (int r = 0; r < 4; r++)
                    sl[wave][qg*16 + g4*4 + r][HF] = accL[qg][r];
        }
        __syncthreads();

        // reduce 8 slices into sred (separate dst -> idempotent)
        {
            int q = tid & 63;
            for (int col = tid >> 6; col < HF + 1; col += 8) {
                float s = sl[0][q][col + zoff2];
                #pragma unroll
                for (int w2 = 1; w2 < WAVES; w2++) s += sl[w2][q][col + zoff2];
                sred[q][col] = s;
            }
        }
        __syncthreads();

        // projection: normalize, Wv, gamma, residual
        int q  = tid & 63;
        int cb = tid >> 6;
        float rL = 1.f / sred[q][HF + zoff2];
        float o_[HF];
        #pragma unroll
        for (int h = 0; h < HF; h++) o_[h] = sred[q][h + zoff2] * rL;
        float gm = gamma[0];
        size_t obase = (size_t)b * CC * NN + n0 + q + zoff2;
        for (int c = cb*8; c < cb*8 + 8; c++) {
            float v = bv[c];
            #pragma unroll
            for (int h = 0; h < HF; h++) v += Wv[c*HF + h] * o_[h];
            size_t a = obase + (size_t)c * NN;
            out[a] = gm * v + x[a];
        }
        __syncthreads();   // protect sred/sl reuse across reps
    }
}

extern "C" void kernel_launch(void* const* d_in, const int* in_sizes, int n_in,
                              void* d_out, int out_size, void* d_ws, size_t ws_size,
                              hipStream_t stream) {
    const float* x     = (const float*)d_in[0];
    const float* Wf    = (const float*)d_in[1];
    const float* bf    = (const float*)d_in[2];
    const float* Wg    = (const float*)d_in[3];
    const float* bg    = (const float*)d_in[4];
    const float* Wh    = (const float*)d_in[5];
    const float* bh    = (const float*)d_in[6];
    const float* Wv    = (const float*)d_in[7];
    const float* bv    = (const float*)d_in[8];
    const float* gamma = (const float*)d_in[9];
    float* out = (float*)d_out;

    unsigned short* ws   = (unsigned short*)d_ws;
    unsigned short* fpk  = ws;                               // B*N*16  u16
    unsigned short* gpk  = ws + (size_t)BB*NN*16;            // B*N*32  u16
    unsigned short* vblk = ws + (size_t)BB*NN*48;            // B*128*1024 u16
    // total 2.62 MB

    proj_kernel<<<(BB*NN/128)*6, 128, 0, stream>>>(x, Wf, bf, Wg, bg, Wh, bh,
                                                   fpk, gpk, vblk);
    attn_kernel<<<BB*(NN/QBLK), THREADS, 0, stream>>>(fpk, gpk, vblk,
                                                      Wv, bv, gamma, x, out);
}

// Round 25
// 28.812 us; speedup vs baseline: 1.4444x; 1.4444x over previous
//
#include <hip/hip_runtime.h>
#include <math.h>

#define BB 4
#define CC 64
#define NN 4096
#define IND 8
#define HF 32
#define QBLK 64
#define THREADS 512
#define WAVES 8
#define MBLK 32
#define MCHUNK (NN/WAVES)    // 512 m's per wave
#define NBLK (MCHUNK/MBLK)   // 16 blocks

typedef __attribute__((ext_vector_type(8))) short bf16x8;
typedef __attribute__((ext_vector_type(4))) float f32x4;

static __device__ __forceinline__ unsigned short f2bf(float x) {
    unsigned int u = __float_as_uint(x);
    u = (u + 0x7FFFu + ((u >> 16) & 1u)) >> 16;   // RNE
    return (unsigned short)u;
}
static __device__ __forceinline__ float bf2f(unsigned short h) {
    return __uint_as_float(((unsigned int)h) << 16);
}
// native __bf16 casts -> v_cvt_pk_bf16_f32 path (R17, kept)
static __device__ __forceinline__ unsigned int pk2(float lo, float hi) {
    __bf16 l = (__bf16)lo, h = (__bf16)hi;
    unsigned short ul = __builtin_bit_cast(unsigned short, l);
    unsigned short uh = __builtin_bit_cast(unsigned short, h);
    return (unsigned int)ul | ((unsigned int)uh << 16);
}
static __device__ __forceinline__ float ex2(float x) {
    return __builtin_amdgcn_exp2f(x);   // v_exp_f32 (2^x)
}

// m -> k-slot coding shared by P (in-register) and V (blocked layout):
// k(m5) = (m5&3) | ((m5>>4)&1)<<2 | ((m5>>2)&3)<<3   (bijective on 0..31)
// V layout: vblk[b][mb][hg][c15][ks] u16 (2 KB per mb) -> contiguous wave-load.
//
// R25: K DEDUP. Old gpk [n][32] = [gh,gh,gl,gl] stored each value twice so
// octet g4 indexed linearly (64 B/m). New gpk [n][16] = [gh(8), gl(8)]
// (32 B/m); A-octet = (g4>>1)*8 gives {gh,gh,gl,gl}[g4] -- identical
// register contents, identical MFMA products, HALF the unique K traffic.
// Theory: loop is per-XCD-L2-BW-bound (each WG streams the full batch
// K+V 512 KB; 16 MB/XCD ~ 8-11 us at ~1.5-2 TB/s effective = measured 11.5).

// Kernel 1: 1x1-conv projections -> packed bf16 workspaces. (R22 form;
// only the og==1 writeout changed for the dedup'd K layout.)
__global__ __launch_bounds__(128) void proj_kernel(
    const float* __restrict__ xsrc,
    const float* __restrict__ Wf, const float* __restrict__ bf,
    const float* __restrict__ Wg, const float* __restrict__ bg,
    const float* __restrict__ Wh, const float* __restrict__ bh,
    unsigned short* __restrict__ fpk,
    unsigned short* __restrict__ gpk,
    unsigned short* __restrict__ vblk)
{
    __shared__ float swT[CC][8];       // [c][o], 2 KB

    int tid = threadIdx.x;
    int bx  = blockIdx.x;
    int og  = bx >> 7;                 // 0..5 (block-uniform)
    int r   = bx & 127;
    int xcd = r & 7;
    int b   = xcd >> 1;
    int blk = ((xcd & 1) << 4) + (r >> 3);
    int n   = blk * 128 + tid;

    const float* W;
    const float* bias;
    if (og == 0)      { W = Wf; bias = bf; }
    else if (og == 1) { W = Wg; bias = bg; }
    else              { W = Wh + (og - 2) * 8 * CC; bias = bh + (og - 2) * 8; }

    // stage W -> LDS transposed (one-time)
    {
        float4 wv = *(const float4*)(W + tid * 4);   // coalesced
        int o = (tid * 4) >> 6;
        int c0 = (tid * 4) & 63;
        swT[c0 + 0][o] = wv.x;
        swT[c0 + 1][o] = wv.y;
        swT[c0 + 2][o] = wv.z;
        swT[c0 + 3][o] = wv.w;
    }

    // issue all 64 coalesced loads, then pin them live before any FMA
    float xv[CC];
    {
        const float* xp = xsrc + (size_t)b * CC * NN + n;
        #pragma unroll
        for (int c = 0; c < CC; c++) xv[c] = xp[(size_t)c * NN];
    }
    #pragma unroll
    for (int c = 0; c < CC; c++) asm volatile("" : "+v"(xv[c]));

    __syncthreads();

    float a[8];
    #pragma unroll
    for (int o = 0; o < 8; o++) a[o] = bias[o];
    #pragma unroll
    for (int c = 0; c < CC; c++) {
        float4 w0 = *(const float4*)&swT[c][0];   // ds_read_b128, broadcast
        float4 w1 = *(const float4*)&swT[c][4];
        float v = xv[c];
        a[0] += w0.x * v; a[1] += w0.y * v; a[2] += w0.z * v; a[3] += w0.w * v;
        a[4] += w1.x * v; a[5] += w1.y * v; a[6] += w1.z * v; a[7] += w1.w * v;
    }

    const float LOG2E = 1.4426950408889634f;
    size_t base = (size_t)b * NN + n;

    if (og == 0) {
        union { unsigned short s[16]; uint4 q[2]; } fo;
        #pragma unroll
        for (int o = 0; o < 8; o++) {
            unsigned short hi = f2bf(a[o]);
            unsigned short lo = f2bf(a[o] - bf2f(hi));
            fo.s[o] = hi; fo.s[8 + o] = lo;
        }
        uint4* fdst = (uint4*)(fpk + base * 16);
        fdst[0] = fo.q[0]; fdst[1] = fo.q[1];
    } else if (og == 1) {
        // dedup'd K: [gh(8), gl(8)] -- 32 B per position
        union { unsigned short s[16]; uint4 q[2]; } go;
        #pragma unroll
        for (int o = 0; o < 8; o++) {
            float gsc = a[o] * LOG2E;              // exp -> exp2 fold
            unsigned short hi = f2bf(gsc);
            unsigned short lo = f2bf(gsc - bf2f(hi));
            go.s[o] = hi; go.s[8 + o] = lo;
        }
        uint4* gdst = (uint4*)(gpk + base * 16);
        gdst[0] = go.q[0]; gdst[1] = go.q[1];
    } else {
        int m5 = n & 31;
        int code = (m5 & 3) | (((m5 >> 4) & 1) << 2) | (((m5 >> 2) & 3) << 3);
        int mb = (n >> 5);                          // m-block within batch
        int h0 = (og - 2) * 8;
        int hg = h0 >> 4;                           // block-uniform
        unsigned short* vp = vblk + (size_t)b * (NN/32) * 1024
                           + (size_t)mb * 1024 + hg * 512 + code;
        #pragma unroll
        for (int o = 0; o < 8; o++)
            vp[((h0 + o) & 15) * 32] = f2bf(a[o]);
    }
}

// Kernel 2: register-only MFMA flash attention + fused Wv/gamma/residual.
// R22 form (2-deep A/B pipeline, setprio, cvt_pk, L-via-ones, vblk V);
// K reads use the dedup'd [gh,gl] layout: octet offset (g4>>1)*8.
__global__ __launch_bounds__(THREADS, 2) void attn_kernel(
    const unsigned short* __restrict__ fpk,
    const unsigned short* __restrict__ gpk,
    const unsigned short* __restrict__ vblk,
    const float* __restrict__ Wv, const float* __restrict__ bv,
    const float* __restrict__ gamma,
    const float* __restrict__ x, float* __restrict__ out)
{
    __shared__ float sl[WAVES][QBLK][HF + 1];   // 8*64*33*4 = 67.6 KB

    int tid  = threadIdx.x;
    int wave = tid >> 6;
    int lane = tid & 63;
    int c15  = lane & 15;
    int g4   = lane >> 4;

    // bijective XCD swizzle: 256 blocks = 8 XCD x 32 contiguous logical ids
    int l  = (blockIdx.x & 7) * 32 + (blockIdx.x >> 3);
    int b  = l >> 6;                  // 64 q-tiles per batch
    int n0 = (l & 63) * QBLK;

    // Q as B-operand: col=c15 -> q = n0+qg*16+c15, k-octet g4 -> [fh,fl,fh,fl]
    bf16x8 bq[4];
    #pragma unroll
    for (int qg = 0; qg < 4; qg++)
        bq[qg] = *(const bf16x8*)(fpk
                  + ((size_t)(b * NN + n0 + qg*16 + c15)) * 16 + (g4 & 1) * 8);

    f32x4 zero4 = {0.f, 0.f, 0.f, 0.f};
    f32x4 acc[4][2];
    f32x4 accL[4];
    #pragma unroll
    for (int qg = 0; qg < 4; qg++) {
        acc[qg][0] = zero4; acc[qg][1] = zero4; accL[qg] = zero4;
    }
    const short one_bf = (short)0x3F80;   // 1.0 bf16
    const bf16x8 vones = {one_bf, one_bf, one_bf, one_bf,
                          one_bf, one_bf, one_bf, one_bf};

    // hoisted per-lane bases; K stride per m = 16 u16 (dedup'd), octet (g4>>1)
    const unsigned short* gp = gpk  + (size_t)b * NN * 16
                             + ((size_t)(wave * MCHUNK + c15)) * 16 + (g4 >> 1) * 8;
    const unsigned short* vp = vblk + (size_t)b * (NN/32) * 1024
                             + (size_t)(wave * NBLK) * 1024 + c15*32 + g4*8;

#define PREFETCH(tt, ak, vb) do {                                   \
        const unsigned short* g_ = gp + (size_t)(tt) * 512;         \
        const unsigned short* v_ = vp + (size_t)(tt) * 1024;        \
        ak[0] = *(const bf16x8*)(g_);                               \
        ak[1] = *(const bf16x8*)(g_ + 256);                         \
        vb[0] = *(const bf16x8*)(v_);                               \
        vb[1] = *(const bf16x8*)(v_ + 512);                         \
    } while (0)

#define COMPUTE(ak, vb) do {                                        \
        f32x4 sf[4][2];                                             \
        __builtin_amdgcn_s_setprio(1);                              \
        _Pragma("unroll")                                           \
        for (int mg = 0; mg < 2; mg++)                              \
            _Pragma("unroll")                                       \
            for (int qg = 0; qg < 4; qg++)                          \
                sf[qg][mg] = __builtin_amdgcn_mfma_f32_16x16x32_bf16( \
                    ak[mg], bq[qg], zero4, 0, 0, 0);                \
        __builtin_amdgcn_s_setprio(0);                              \
        bf16x8 pa[4];                                               \
        _Pragma("unroll")                                           \
        for (int qg = 0; qg < 4; qg++) {                            \
            float e00 = ex2(sf[qg][0][0]), e01 = ex2(sf[qg][0][1]); \
            float e02 = ex2(sf[qg][0][2]), e03 = ex2(sf[qg][0][3]); \
            float e10 = ex2(sf[qg][1][0]), e11 = ex2(sf[qg][1][1]); \
            float e12 = ex2(sf[qg][1][2]), e13 = ex2(sf[qg][1][3]); \
            union { unsigned int u[4]; bf16x8 v; } pp;              \
            pp.u[0] = pk2(e00, e01); pp.u[1] = pk2(e02, e03);       \
            pp.u[2] = pk2(e10, e11); pp.u[3] = pk2(e12, e13);       \
            pa[qg] = pp.v;                                          \
        }                                                           \
        __builtin_amdgcn_s_setprio(1);                              \
        _Pragma("unroll")                                           \
        for (int qg = 0; qg < 4; qg++) {                            \
            _Pragma("unroll")                                       \
            for (int hg = 0; hg < 2; hg++)                          \
                acc[qg][hg] = __builtin_amdgcn_mfma_f32_16x16x32_bf16( \
                    pa[qg], vb[hg], acc[qg][hg], 0, 0, 0);          \
            accL[qg] = __builtin_amdgcn_mfma_f32_16x16x32_bf16(     \
                    pa[qg], vones, accL[qg], 0, 0, 0);              \
        }                                                           \
        __builtin_amdgcn_s_setprio(0);                              \
    } while (0)

    bf16x8 akA[2], vbA[2], akB[2], vbB[2];
    PREFETCH(0, akA, vbA);

    #pragma unroll 2
    for (int tp = 0; tp < NBLK; tp += 2) {
        PREFETCH(tp + 1, akB, vbB);          // tp+1 <= 15: always valid
        COMPUTE(akA, vbA);                   // even t
        if (tp + 2 < NBLK) PREFETCH(tp + 2, akA, vbA);
        COMPUTE(akB, vbB);                   // odd t
    }
#undef PREFETCH
#undef COMPUTE

    // ---- deterministic wave combine (no atomics) ----
    #pragma unroll
    for (int qg = 0; qg < 4; qg++)
        #pragma unroll
        for (int hg = 0; hg < 2; hg++)
            #pragma unroll
            for (int r = 0; r < 4; r++)
                sl[wave][qg*16 + g4*4 + r][hg*16 + c15] = acc[qg][hg][r];
    // L: every c15 lane holds the same row-sum; c15==0 writes it
    if (c15 == 0) {
        #pragma unroll
        for (int qg = 0; qg < 4; qg++)
            #pragma unroll
            for (int r = 0; r < 4; r++)
                sl[wave][qg*16 + g4*4 + r][HF] = accL[qg][r];
    }
    __syncthreads();

    // sum the 8 wave slices into slice 0: 512 threads over 64 q x 33 cols
    {
        int q = tid & 63;
        for (int col = tid >> 6; col < HF + 1; col += 8) {
            float s = sl[0][q][col];
            #pragma unroll
            for (int w2 = 1; w2 < WAVES; w2++) s += sl[w2][q][col];
            sl[0][q][col] = s;
        }
    }
    __syncthreads();

    // epilogue: normalize, Wv projection, gamma, residual
    // 512 threads = 64 q x 8 channel-blocks of 8
    int q  = tid & 63;
    int cb = tid >> 6;
    float rL = 1.f / sl[0][q][HF];
    float o_[HF];
    #pragma unroll
    for (int h = 0; h < HF; h++) o_[h] = sl[0][q][h] * rL;
    float gm = gamma[0];
    size_t obase = (size_t)b * CC * NN + n0 + q;
    for (int c = cb*8; c < cb*8 + 8; c++) {
        float v = bv[c];
        #pragma unroll
        for (int h = 0; h < HF; h++) v += Wv[c*HF + h] * o_[h];
        size_t a = obase + (size_t)c * NN;
        out[a] = gm * v + x[a];
    }
}

extern "C" void kernel_launch(void* const* d_in, const int* in_sizes, int n_in,
                              void* d_out, int out_size, void* d_ws, size_t ws_size,
                              hipStream_t stream) {
    const float* x     = (const float*)d_in[0];
    const float* Wf    = (const float*)d_in[1];
    const float* bf    = (const float*)d_in[2];
    const float* Wg    = (const float*)d_in[3];
    const float* bg    = (const float*)d_in[4];
    const float* Wh    = (const float*)d_in[5];
    const float* bh    = (const float*)d_in[6];
    const float* Wv    = (const float*)d_in[7];
    const float* bv    = (const float*)d_in[8];
    const float* gamma = (const float*)d_in[9];
    float* out = (float*)d_out;

    unsigned short* ws   = (unsigned short*)d_ws;
    unsigned short* fpk  = ws;                               // B*N*16  u16
    unsigned short* gpk  = ws + (size_t)BB*NN*16;            // B*N*16  u16 (dedup'd)
    unsigned short* vblk = ws + (size_t)BB*NN*32;            // B*128*1024 u16
    // total 2.1 MB

    proj_kernel<<<(BB*NN/128)*6, 128, 0, stream>>>(x, Wf, bf, Wg, bg, Wh, bh,
                                                   fpk, gpk, vblk);
    attn_kernel<<<BB*(NN/QBLK), THREADS, 0, stream>>>(fpk, gpk, vblk,
                                                      Wv, bv, gamma, x, out);
}